// Round 15
// baseline (422.393 us; speedup 1.0000x reference)
//
#include <hip/hip_runtime.h>

#define N_NODES 100000
#define E_EDGES 1600000
#define IN_C 256
#define HID_C 128
#define BN_EPS 1e-5f

#define NBUCK 391                      // buckets of 256 nodes: dst >> 8
#define BIN_BLOCKS 256
#define CHUNK (E_EDGES / BIN_BLOCKS)   // 6250
#define HW 392                         // segment-table row width (incl. sentinel)
#define AGG_BLOCKS 2048                // aggregate grid: 256 chunks x 8 slices
#define GB1 782                        // gemm1 blocks: 128 rows each
#define GB2 782                        // gemm2 blocks: 128 rows each
#define WPERM_BLOCKS 97                // 49280 permute elems / 512
#define SL ((size_t)N_NODES * 16)      // slice region size in ushorts (16 ch/slice)

typedef unsigned int uint_t;
using v8s = __attribute__((ext_vector_type(8))) short;
using v4f = __attribute__((ext_vector_type(4))) float;

__device__ __forceinline__ unsigned short f2bf(float f) {
    unsigned int u = __float_as_uint(f);
    u += 0x7fffu + ((u >> 16) & 1u);
    return (unsigned short)(u >> 16);
}

__device__ __forceinline__ void fma8(uint4 u, float w, float* a) {
    a[0] += __uint_as_float(u.x << 16) * w;
    a[1] += __uint_as_float(u.x & 0xffff0000u) * w;
    a[2] += __uint_as_float(u.y << 16) * w;
    a[3] += __uint_as_float(u.y & 0xffff0000u) * w;
    a[4] += __uint_as_float(u.z << 16) * w;
    a[5] += __uint_as_float(u.z & 0xffff0000u) * w;
    a[6] += __uint_as_float(u.w << 16) * w;
    a[7] += __uint_as_float(u.w & 0xffff0000u) * w;
}

// ---------- edge index accessors ----------
__device__ __forceinline__ int edge_src(const int* ei, int e, int is64) {
    return is64 ? ei[2 * e] : ei[e];
}
__device__ __forceinline__ int edge_dst(const int* ei, int e, int is64) {
    return is64 ? ei[2 * E_EDGES + 2 * e] : ei[E_EDGES + e];
}

// ---------- bin (blocks<256: counting sort by dst>>8, inline dtype detect)
//            + wperm role (blocks >= 256) ----------
__global__ __launch_bounds__(512) void bin_kernel(
    const int* __restrict__ ei, uint_t* __restrict__ ebuf, int* __restrict__ H,
    int* __restrict__ part,
    const float* __restrict__ W1, const float* __restrict__ W2,
    const float* __restrict__ W3, const float* __restrict__ b2,
    const float* __restrict__ b3,
    unsigned short* __restrict__ W1p, unsigned short* __restrict__ Wcp,
    float* __restrict__ bcat) {
    if (blockIdx.x >= BIN_BLOCKS) {
        int t = (blockIdx.x - BIN_BLOCKS) * 512 + threadIdx.x;
        if (t < 32768) {                       // W1p: K=256
            int j = t & 7, l = (t >> 3) & 63, ct = (t >> 9) & 7, kt = t >> 12;
            int k = kt * 32 + ((l >> 4) << 2) + (j & 3) + ((j >> 2) << 4);
            int n = ct * 16 + (l & 15);
            W1p[t] = f2bf(W1[k * 128 + n]);
        } else if (t < 49152) {                // Wcp: K=128, cols = [W2|W3]
            int u = t - 32768;
            int j = u & 7, l = (u >> 3) & 63, ct = (u >> 9) & 7, kt = u >> 12;
            int k = kt * 32 + ((l >> 4) << 2) + (j & 3) + ((j >> 2) << 4);
            int n = ct * 16 + (l & 15);
            float v = (n < 64) ? W2[k * 64 + n] : W3[k * 64 + (n - 64)];
            Wcp[u] = f2bf(v);
        } else if (t < 49280) {
            int c = t - 49152;
            bcat[c] = (c < 64) ? b2[c] : b3[c - 64];
        }
        return;
    }
    __shared__ int sh[512];
    __shared__ int cur[512];
    __shared__ int anyw;
    int tid = threadIdx.x;
    int base = blockIdx.x * CHUNK;
    if (tid == 0) anyw = 0;
    sh[tid] = 0;
    __syncthreads();
    if (ei[2 * (base + tid) + 1] != 0) atomicOr(&anyw, 1);
    __syncthreads();
    int is64 = anyw ? 0 : 1;
    for (int i = tid; i < CHUNK; i += 512)
        atomicAdd(&sh[edge_dst(ei, base + i, is64) >> 8], 1);
    __syncthreads();
    int c0 = sh[tid];
    if (tid < NBUCK && c0 > 0) atomicAdd(&part[tid], c0);
    for (int off = 1; off < 512; off <<= 1) {
        int a0 = (tid >= off) ? sh[tid - off] : 0;
        __syncthreads();
        sh[tid] += a0;
        __syncthreads();
    }
    int ex = sh[tid] - c0;
    cur[tid] = ex;
    if (tid < HW) H[blockIdx.x * HW + tid] = ex;
    __syncthreads();
    for (int i = tid; i < CHUNK; i += 512) {
        int e = base + i;
        int s = edge_src(ei, e, is64);
        int d = edge_dst(ei, e, is64);
        int pos = base + atomicAdd(&cur[d >> 8], 1);
        ebuf[pos] = ((uint_t)s << 8) | (uint_t)(d & 255);
    }
}

// ---------- fused (512 thr): {bucket hist + scan + csr fill} || GEMM1 ----------
// GEMM1 writes hbf SLICE-MAJOR: hbf[ct*SL + row*16 + (ch%16)]
__global__ __launch_bounds__(512) void scanfill_and_gemm1(
    const uint_t* __restrict__ ebuf, const int* __restrict__ H,
    const int* __restrict__ part, int* __restrict__ rowptr,
    float* __restrict__ dis, int* __restrict__ csr_src,
    const float* __restrict__ x, const unsigned short* __restrict__ W1p,
    unsigned short* __restrict__ hbf) {
    __shared__ uint4 smemB[2048];          // 32KB (gemm role); aliased by scan role
    if (blockIdx.x < NBUCK) {
        int* segbeg = (int*)smemB;
        int* seglen = segbeg + 256;
        int* hist   = seglen + 256;
        int* sc     = hist + 256;
        int* cur    = sc + 256;
        int* red    = cur + 256;
        int t = threadIdx.x, b = blockIdx.x;
        if (t < 256) {
            int h0 = H[t * HW + b], h1 = H[t * HW + b + 1];
            segbeg[t] = t * CHUNK + h0;
            seglen[t] = h1 - h0;
            hist[t] = 0;
        }
        __syncthreads();
        int wv = t >> 6, lane = t & 63;
        int sg = lane >> 4, sl = lane & 15;
        for (int s = wv * 4 + sg; s < BIN_BLOCKS; s += 32) {
            int len = seglen[s], beg = segbeg[s];
            for (int j = sl; j < len; j += 16)
                atomicAdd(&hist[ebuf[beg + j] & 255], 1);
        }
        __syncthreads();
        int partial = 0;
        for (int i = t; i < b; i += 512) partial += part[i];
        red[t] = partial;
        __syncthreads();
        for (int off = 256; off > 0; off >>= 1) {
            if (t < off) red[t] += red[t + off];
            __syncthreads();
        }
        int goff = red[0];
        if (t < 256) sc[t] = hist[t];
        __syncthreads();
        for (int off = 1; off < 256; off <<= 1) {
            int a = (t < 256 && t >= off) ? sc[t - off] : 0;
            __syncthreads();
            if (t < 256) sc[t] += a;
            __syncthreads();
        }
        if (t < 256) {
            int deg = hist[t];
            int n = b * 256 + t;
            int rp = goff + sc[t] - deg;
            if (n < N_NODES) {
                rowptr[n] = rp;
                dis[n] = rsqrtf(1.0f + (float)deg);
            }
            cur[t] = rp;
        }
        if (b == 0 && t == 0) rowptr[N_NODES] = E_EDGES;
        __syncthreads();
        for (int s = wv * 4 + sg; s < BIN_BLOCKS; s += 32) {
            int len = seglen[s], beg = segbeg[s];
            for (int j = sl; j < len; j += 16) {
                uint_t v = ebuf[beg + j];
                int pos = atomicAdd(&cur[v & 255], 1);
                csr_src[pos] = (int)(v >> 8);
            }
        }
        return;
    }
    // ---- GEMM1 role: 128 rows/block, W1p staged in 2x 32KB halves ----
    int bid = blockIdx.x - NBUCK;
    int wave = threadIdx.x >> 6;
    int l = threadIdx.x & 63;
    int kg = l >> 4;
    int row = bid * 128 + wave * 16 + (l & 15);
    int rl = min(row, N_NODES - 1);
    const float* xr = x + (size_t)rl * IN_C + kg * 4;

    v4f acc[8];
    #pragma unroll
    for (int i = 0; i < 8; ++i)
        for (int r = 0; r < 4; ++r) acc[i][r] = 0.f;

    #pragma unroll
    for (int half = 0; half < 2; ++half) {
        __syncthreads();
        for (int i = threadIdx.x; i < 2048; i += 512)
            smemB[i] = ((const uint4*)W1p)[half * 2048 + i];
        float4 pa[4][2];
        #pragma unroll
        for (int i = 0; i < 4; ++i) {
            pa[i][0] = *(const float4*)(xr + (half * 4 + i) * 32);
            pa[i][1] = *(const float4*)(xr + (half * 4 + i) * 32 + 16);
        }
        __syncthreads();
        #pragma unroll
        for (int k4 = 0; k4 < 4; ++k4) {
            float4 u = pa[k4][0], v = pa[k4][1];
            v8s a;
            a[0] = f2bf(u.x); a[1] = f2bf(u.y); a[2] = f2bf(u.z); a[3] = f2bf(u.w);
            a[4] = f2bf(v.x); a[5] = f2bf(v.y); a[6] = f2bf(v.z); a[7] = f2bf(v.w);
            #pragma unroll
            for (int ct = 0; ct < 8; ++ct) {
                v8s b = ((const v8s*)smemB)[(k4 * 8 + ct) * 64 + l];
                acc[ct] = __builtin_amdgcn_mfma_f32_16x16x32_bf16(a, b, acc[ct], 0, 0, 0);
            }
        }
    }
    int orow0 = bid * 128 + wave * 16 + kg * 4;
    #pragma unroll
    for (int ct = 0; ct < 8; ++ct) {
        #pragma unroll
        for (int r = 0; r < 4; ++r) {
            int orow = orow0 + r;
            if (orow < N_NODES)
                hbf[(size_t)ct * SL + (size_t)orow * 16 + (l & 15)] = f2bf(acc[ct][r]);
        }
    }
}

// ---------- XCD-sliced aggregation ----------
// slice = blockIdx&7 (XCD-affine). Table slice-major: tbl[s*SL + node*16 + c].
// 16-lane quarter per node, lane = edge (16 x 32B gathers in flight).
// SPLIT=0: bf16 slice-major out + per-slice BN partials. SPLIT=1: split fp32 out.
template <int SPLIT>
__global__ __launch_bounds__(256) void aggregate_s(const unsigned short* __restrict__ tbl,
                                                   const int* __restrict__ csr_src,
                                                   const int* __restrict__ rowptr,
                                                   const float* __restrict__ dis,
                                                   const float* __restrict__ bias,
                                                   void* __restrict__ outp,
                                                   float* __restrict__ partials) {
    const int s = blockIdx.x & 7;
    const int chunk = blockIdx.x >> 3;             // 0..255
    const int q = threadIdx.x >> 4;                // quarter 0..15
    const int ql = threadIdx.x & 15;
    const unsigned short* slice = tbl + (size_t)s * SL;

    // per-lane bias registers (writer lanes only use them)
    float4 bsa = {0, 0, 0, 0}, bsb = {0, 0, 0, 0};
    if (SPLIT == 0) {
        if (ql < 2) {
            bsa = *(const float4*)&bias[s * 16 + ql * 8];
            bsb = *(const float4*)&bias[s * 16 + ql * 8 + 4];
        }
    } else {
        if (ql < 4) bsa = *(const float4*)&bias[s * 16 + ql * 4];
    }
    float sums[8] = {}, sumsq[8] = {};

    for (int wid = chunk * 16 + q; wid < N_NODES; wid += 4096) {
        int beg = rowptr[wid], end = rowptr[wid + 1];
        float dn = dis[wid];
        float acc[16] = {};
        if (ql < 2) {                              // self term, 8 ch per lane
            uint4 su = *(const uint4*)(slice + (size_t)wid * 16 + ql * 8);
            if (ql == 0) fma8(su, dn * dn, acc);
            else         fma8(su, dn * dn, acc + 8);
        }
        for (int c = beg + ql; c < end; c += 16) { // lane = edge
            int src = csr_src[c];
            float w = dis[src] * dn;
            const uint4* mp = (const uint4*)(slice + (size_t)src * 16);
            uint4 m0 = mp[0], m1 = mp[1];
            fma8(m0, w, acc);
            fma8(m1, w, acc + 8);
        }
        // butterfly reduce across the 16-lane quarter
        #pragma unroll
        for (int k = 0; k < 16; ++k) {
            acc[k] += __shfl_xor(acc[k], 1);
            acc[k] += __shfl_xor(acc[k], 2);
            acc[k] += __shfl_xor(acc[k], 4);
            acc[k] += __shfl_xor(acc[k], 8);
        }
        if (SPLIT == 0) {
            if (ql < 2) {
                float v0, v1, v2, v3, v4, v5, v6, v7;
                if (ql == 0) { v0 = acc[0]; v1 = acc[1]; v2 = acc[2]; v3 = acc[3];
                               v4 = acc[4]; v5 = acc[5]; v6 = acc[6]; v7 = acc[7]; }
                else         { v0 = acc[8]; v1 = acc[9]; v2 = acc[10]; v3 = acc[11];
                               v4 = acc[12]; v5 = acc[13]; v6 = acc[14]; v7 = acc[15]; }
                v0 += bsa.x; v1 += bsa.y; v2 += bsa.z; v3 += bsa.w;
                v4 += bsb.x; v5 += bsb.y; v6 += bsb.z; v7 += bsb.w;
                uint4 o;
                o.x = ((uint_t)f2bf(v1) << 16) | f2bf(v0);
                o.y = ((uint_t)f2bf(v3) << 16) | f2bf(v2);
                o.z = ((uint_t)f2bf(v5) << 16) | f2bf(v4);
                o.w = ((uint_t)f2bf(v7) << 16) | f2bf(v6);
                *(uint4*)((unsigned short*)outp + (size_t)s * SL + (size_t)wid * 16 + ql * 8) = o;
                sums[0] += v0; sumsq[0] += v0 * v0;
                sums[1] += v1; sumsq[1] += v1 * v1;
                sums[2] += v2; sumsq[2] += v2 * v2;
                sums[3] += v3; sumsq[3] += v3 * v3;
                sums[4] += v4; sumsq[4] += v4 * v4;
                sums[5] += v5; sumsq[5] += v5 * v5;
                sums[6] += v6; sumsq[6] += v6 * v6;
                sums[7] += v7; sumsq[7] += v7 * v7;
            }
        } else {
            if (ql < 4) {
                float v0, v1, v2, v3;
                if (ql == 0)      { v0 = acc[0];  v1 = acc[1];  v2 = acc[2];  v3 = acc[3]; }
                else if (ql == 1) { v0 = acc[4];  v1 = acc[5];  v2 = acc[6];  v3 = acc[7]; }
                else if (ql == 2) { v0 = acc[8];  v1 = acc[9];  v2 = acc[10]; v3 = acc[11]; }
                else              { v0 = acc[12]; v1 = acc[13]; v2 = acc[14]; v3 = acc[15]; }
                float4 o = {v0 + bsa.x, v1 + bsa.y, v2 + bsa.z, v3 + bsa.w};
                float* out = (float*)outp;
                size_t base = (s < 4) ? ((size_t)wid * 64 + s * 16 + ql * 4)
                                      : ((size_t)(N_NODES + wid) * 64 + (s - 4) * 16 + ql * 4);
                *(float4*)(out + base) = o;
            }
        }
    }
    if (SPLIT == 0) {
        __shared__ float reds[16][16], redq[16][16];
        if (ql < 2) {
            #pragma unroll
            for (int j = 0; j < 8; ++j) {
                reds[q][ql * 8 + j] = sums[j];
                redq[q][ql * 8 + j] = sumsq[j];
            }
        }
        __syncthreads();
        if (threadIdx.x < 16) {
            float a = 0.f, b = 0.f;
            #pragma unroll
            for (int qq = 0; qq < 16; ++qq) { a += reds[qq][threadIdx.x]; b += redq[qq][threadIdx.x]; }
            partials[blockIdx.x * 32 + threadIdx.x] = a;
            partials[blockIdx.x * 32 + 16 + threadIdx.x] = b;
        }
    }
}

// ---------- BN reduce: one block per channel; blocks of slice s are b = chunk*8+s ----------
__global__ __launch_bounds__(256) void bn_reduce(const float* __restrict__ partials,
                                                 const float* __restrict__ gamma,
                                                 const float* __restrict__ beta,
                                                 float* __restrict__ bnab) {
    __shared__ float rs[256], rq[256];
    int c = blockIdx.x, t = threadIdx.x;
    int s = c >> 4, off = c & 15;
    rs[t] = partials[(size_t)(t * 8 + s) * 32 + off];
    rq[t] = partials[(size_t)(t * 8 + s) * 32 + 16 + off];
    __syncthreads();
    for (int o = 128; o > 0; o >>= 1) {
        if (t < o) { rs[t] += rs[t + o]; rq[t] += rq[t + o]; }
        __syncthreads();
    }
    if (t == 0) {
        float mean = rs[0] * (1.0f / N_NODES);
        float var = rq[0] * (1.0f / N_NODES) - mean * mean;
        float scale = rsqrtf(var + BN_EPS) * gamma[c];
        bnab[c] = scale;
        bnab[128 + c] = beta[c] - mean * scale;
    }
}

// ---------- GEMM2 (512 threads): slice-major bf16 in/out, BN+ReLU fused on A ----------
__global__ __launch_bounds__(512) void gemm2_bn_mfma(const unsigned short* __restrict__ h2,
                                                     const float* __restrict__ bnab,
                                                     const unsigned short* __restrict__ Wp,
                                                     unsigned short* __restrict__ Cb) {
    __shared__ uint4 wlds[2048];           // 32KB: full Wcp
    __shared__ float ss[256];
    for (int i = threadIdx.x; i < 2048; i += 512) wlds[i] = ((const uint4*)Wp)[i];
    if (threadIdx.x < 256) ss[threadIdx.x] = bnab[threadIdx.x];
    __syncthreads();

    int wave = threadIdx.x >> 6;
    int l = threadIdx.x & 63;
    int kg = l >> 4;
    int row = blockIdx.x * 128 + wave * 16 + (l & 15);
    int rl = min(row, N_NODES - 1);

    v4f acc[8];
    #pragma unroll
    for (int i = 0; i < 8; ++i)
        for (int r = 0; r < 4; ++r) acc[i][r] = 0.f;

    uint2 pa[4][2];
    #pragma unroll
    for (int i = 0; i < 4; ++i) {
        pa[i][0] = *(const uint2*)(h2 + (size_t)(2 * i) * SL + (size_t)rl * 16 + kg * 4);
        pa[i][1] = *(const uint2*)(h2 + (size_t)(2 * i + 1) * SL + (size_t)rl * 16 + kg * 4);
    }
    #pragma unroll
    for (int kt = 0; kt < HID_C / 32; ++kt) {
        int k0 = kt * 32 + kg * 4;
        float4 sc0 = *(const float4*)&ss[k0];
        float4 sh0 = *(const float4*)&ss[128 + k0];
        float4 sc1 = *(const float4*)&ss[k0 + 16];
        float4 sh1 = *(const float4*)&ss[128 + k0 + 16];
        uint2 p0 = pa[kt][0], p1 = pa[kt][1];
        float v0 = __uint_as_float(p0.x << 16), v1 = __uint_as_float(p0.x & 0xffff0000u);
        float v2 = __uint_as_float(p0.y << 16), v3 = __uint_as_float(p0.y & 0xffff0000u);
        float v4 = __uint_as_float(p1.x << 16), v5 = __uint_as_float(p1.x & 0xffff0000u);
        float v6 = __uint_as_float(p1.y << 16), v7 = __uint_as_float(p1.y & 0xffff0000u);
        v8s a;
        a[0] = f2bf(fmaxf(v0 * sc0.x + sh0.x, 0.f));
        a[1] = f2bf(fmaxf(v1 * sc0.y + sh0.y, 0.f));
        a[2] = f2bf(fmaxf(v2 * sc0.z + sh0.z, 0.f));
        a[3] = f2bf(fmaxf(v3 * sc0.w + sh0.w, 0.f));
        a[4] = f2bf(fmaxf(v4 * sc1.x + sh1.x, 0.f));
        a[5] = f2bf(fmaxf(v5 * sc1.y + sh1.y, 0.f));
        a[6] = f2bf(fmaxf(v6 * sc1.z + sh1.z, 0.f));
        a[7] = f2bf(fmaxf(v7 * sc1.w + sh1.w, 0.f));
        #pragma unroll
        for (int ct = 0; ct < 8; ++ct) {
            v8s b = ((const v8s*)wlds)[(kt * 8 + ct) * 64 + l];
            acc[ct] = __builtin_amdgcn_mfma_f32_16x16x32_bf16(a, b, acc[ct], 0, 0, 0);
        }
    }
    int orow0 = blockIdx.x * 128 + wave * 16 + kg * 4;
    #pragma unroll
    for (int ct = 0; ct < 8; ++ct) {
        #pragma unroll
        for (int r = 0; r < 4; ++r) {
            int orow = orow0 + r;
            if (orow < N_NODES)
                Cb[(size_t)ct * SL + (size_t)orow * 16 + (l & 15)] = f2bf(acc[ct][r]);
        }
    }
}

extern "C" void kernel_launch(void* const* d_in, const int* in_sizes, int n_in,
                              void* d_out, int out_size, void* d_ws, size_t ws_size,
                              hipStream_t stream) {
    const float* x    = (const float*)d_in[0];
    const int* ei     = (const int*)d_in[1];
    const float* W1   = (const float*)d_in[2];
    const float* b1   = (const float*)d_in[3];
    const float* gamma= (const float*)d_in[4];
    const float* beta = (const float*)d_in[5];
    const float* W2   = (const float*)d_in[6];
    const float* b2   = (const float*)d_in[7];
    const float* W3   = (const float*)d_in[8];
    const float* b3   = (const float*)d_in[9];
    float* out = (float*)d_out;

    char* p = (char*)d_ws;
    auto alloc = [&](size_t bytes) {
        void* r = (void*)p;
        p += (bytes + 511) & ~(size_t)511;
        return r;
    };
    float* dis    = (float*)alloc(N_NODES * 4);
    int*   rowptr = (int*)  alloc((N_NODES + 1) * 4);
    int*   part   = (int*)  alloc(2048);
    float* bnab   = (float*)alloc(1024);
    float* bcat   = (float*)alloc(512);
    unsigned short* W1p = (unsigned short*)alloc(256 * 128 * 2);
    unsigned short* Wcp = (unsigned short*)alloc(128 * 128 * 2);
    int*   H      = (int*)  alloc((size_t)BIN_BLOCKS * HW * 4);
    uint_t* ebuf  = (uint_t*)alloc((size_t)E_EDGES * 4);
    int*   csrs   = (int*)  alloc((size_t)E_EDGES * 4);
    unsigned short* hbf  = (unsigned short*)alloc((size_t)N_NODES * 128 * 2);  // gemm1/gemm2 out (slice-major)
    unsigned short* h2bf = (unsigned short*)alloc((size_t)N_NODES * 128 * 2);  // agg1 out (slice-major)
    float* partials = (float*)alloc((size_t)AGG_BLOCKS * 32 * 4);

    hipMemsetAsync(part, 0, 2048, stream);

    // edge binning (+inline dtype detect, +global bucket counts) || weight permutes
    bin_kernel<<<BIN_BLOCKS + WPERM_BLOCKS, 512, 0, stream>>>(
        ei, ebuf, H, part, W1, W2, W3, b2, b3, W1p, Wcp, bcat);

    // {bucket hist + scan + csr fill} || GEMM1 (slice-major out)
    scanfill_and_gemm1<<<NBUCK + GB1, 512, 0, stream>>>(ebuf, H, part, rowptr, dis, csrs,
                                                        x, W1p, hbf);

    // layer 1 aggregate (XCD-sliced) + BN partials; emits bf16 slice-major
    aggregate_s<0><<<AGG_BLOCKS, 256, 0, stream>>>(hbf, csrs, rowptr, dis, b1,
                                                   (void*)h2bf, partials);
    bn_reduce<<<128, 256, 0, stream>>>(partials, gamma, beta, bnab);

    // layer 2: BN+ReLU fused into GEMM2 (slice-major in/out)
    gemm2_bn_mfma<<<GB2, 512, 0, stream>>>(h2bf, bnab, Wcp, hbf);
    aggregate_s<1><<<AGG_BLOCKS, 256, 0, stream>>>(hbf, csrs, rowptr, dis, bcat,
                                                   (void*)out, partials);
}

// Round 16
// 368.610 us; speedup vs baseline: 1.1459x; 1.1459x over previous
//
#include <hip/hip_runtime.h>

#define N_NODES 100000
#define E_EDGES 1600000
#define IN_C 256
#define HID_C 128
#define BN_EPS 1e-5f

#define NBUCK 391                      // buckets of 256 nodes: dst >> 8
#define BIN_BLOCKS 256
#define CHUNK (E_EDGES / BIN_BLOCKS)   // 6250
#define HW 392                         // segment-table row width (incl. sentinel)
#define AGG_BLOCKS 2048                // aggregate grid: 256 chunks x 8 slices
#define GB1 782                        // gemm1 blocks: 128 rows each
#define GB2 782                        // gemm2 blocks: 128 rows each
#define WPERM_BLOCKS 97                // 49280 permute elems / 512
#define SL ((size_t)N_NODES * 16)      // slice region size in ushorts (16 ch/slice)

typedef unsigned int uint_t;
using v8s = __attribute__((ext_vector_type(8))) short;
using v4f = __attribute__((ext_vector_type(4))) float;

__device__ __forceinline__ unsigned short f2bf(float f) {
    unsigned int u = __float_as_uint(f);
    u += 0x7fffu + ((u >> 16) & 1u);
    return (unsigned short)(u >> 16);
}

__device__ __forceinline__ void fma8(uint4 u, float w, float* a) {
    a[0] += __uint_as_float(u.x << 16) * w;
    a[1] += __uint_as_float(u.x & 0xffff0000u) * w;
    a[2] += __uint_as_float(u.y << 16) * w;
    a[3] += __uint_as_float(u.y & 0xffff0000u) * w;
    a[4] += __uint_as_float(u.z << 16) * w;
    a[5] += __uint_as_float(u.z & 0xffff0000u) * w;
    a[6] += __uint_as_float(u.w << 16) * w;
    a[7] += __uint_as_float(u.w & 0xffff0000u) * w;
}

// ---------- edge index accessors ----------
__device__ __forceinline__ int edge_src(const int* ei, int e, int is64) {
    return is64 ? ei[2 * e] : ei[e];
}
__device__ __forceinline__ int edge_dst(const int* ei, int e, int is64) {
    return is64 ? ei[2 * E_EDGES + 2 * e] : ei[E_EDGES + e];
}

// ---------- bin (blocks<256: counting sort by dst>>8, inline dtype detect)
//            + wperm role (blocks >= 256) ----------
__global__ __launch_bounds__(512) void bin_kernel(
    const int* __restrict__ ei, uint_t* __restrict__ ebuf, int* __restrict__ H,
    int* __restrict__ part,
    const float* __restrict__ W1, const float* __restrict__ W2,
    const float* __restrict__ W3, const float* __restrict__ b2,
    const float* __restrict__ b3,
    unsigned short* __restrict__ W1p, unsigned short* __restrict__ Wcp,
    float* __restrict__ bcat) {
    if (blockIdx.x >= BIN_BLOCKS) {
        int t = (blockIdx.x - BIN_BLOCKS) * 512 + threadIdx.x;
        if (t < 32768) {                       // W1p: K=256
            int j = t & 7, l = (t >> 3) & 63, ct = (t >> 9) & 7, kt = t >> 12;
            int k = kt * 32 + ((l >> 4) << 2) + (j & 3) + ((j >> 2) << 4);
            int n = ct * 16 + (l & 15);
            W1p[t] = f2bf(W1[k * 128 + n]);
        } else if (t < 49152) {                // Wcp: K=128, cols = [W2|W3]
            int u = t - 32768;
            int j = u & 7, l = (u >> 3) & 63, ct = (u >> 9) & 7, kt = u >> 12;
            int k = kt * 32 + ((l >> 4) << 2) + (j & 3) + ((j >> 2) << 4);
            int n = ct * 16 + (l & 15);
            float v = (n < 64) ? W2[k * 64 + n] : W3[k * 64 + (n - 64)];
            Wcp[u] = f2bf(v);
        } else if (t < 49280) {
            int c = t - 49152;
            bcat[c] = (c < 64) ? b2[c] : b3[c - 64];
        }
        return;
    }
    __shared__ int sh[512];
    __shared__ int cur[512];
    __shared__ int anyw;
    int tid = threadIdx.x;
    int base = blockIdx.x * CHUNK;
    if (tid == 0) anyw = 0;
    sh[tid] = 0;
    __syncthreads();
    if (ei[2 * (base + tid) + 1] != 0) atomicOr(&anyw, 1);
    __syncthreads();
    int is64 = anyw ? 0 : 1;
    for (int i = tid; i < CHUNK; i += 512)
        atomicAdd(&sh[edge_dst(ei, base + i, is64) >> 8], 1);
    __syncthreads();
    int c0 = sh[tid];
    if (tid < NBUCK && c0 > 0) atomicAdd(&part[tid], c0);
    for (int off = 1; off < 512; off <<= 1) {
        int a0 = (tid >= off) ? sh[tid - off] : 0;
        __syncthreads();
        sh[tid] += a0;
        __syncthreads();
    }
    int ex = sh[tid] - c0;
    cur[tid] = ex;
    if (tid < HW) H[blockIdx.x * HW + tid] = ex;
    __syncthreads();
    for (int i = tid; i < CHUNK; i += 512) {
        int e = base + i;
        int s = edge_src(ei, e, is64);
        int d = edge_dst(ei, e, is64);
        int pos = base + atomicAdd(&cur[d >> 8], 1);
        ebuf[pos] = ((uint_t)s << 8) | (uint_t)(d & 255);
    }
}

// ---------- fused (512 thr): {bucket hist + scan + csr fill} || GEMM1 ----------
// GEMM1 writes hbf SLICE-MAJOR: hbf[ct*SL + row*16 + (ch%16)]
__global__ __launch_bounds__(512) void scanfill_and_gemm1(
    const uint_t* __restrict__ ebuf, const int* __restrict__ H,
    const int* __restrict__ part, int* __restrict__ rowptr,
    float* __restrict__ dis, int* __restrict__ csr_src,
    const float* __restrict__ x, const unsigned short* __restrict__ W1p,
    unsigned short* __restrict__ hbf) {
    __shared__ uint4 smemB[2048];          // 32KB (gemm role); aliased by scan role
    if (blockIdx.x < NBUCK) {
        int* segbeg = (int*)smemB;
        int* seglen = segbeg + 256;
        int* hist   = seglen + 256;
        int* sc     = hist + 256;
        int* cur    = sc + 256;
        int* red    = cur + 256;
        int t = threadIdx.x, b = blockIdx.x;
        if (t < 256) {
            int h0 = H[t * HW + b], h1 = H[t * HW + b + 1];
            segbeg[t] = t * CHUNK + h0;
            seglen[t] = h1 - h0;
            hist[t] = 0;
        }
        __syncthreads();
        int wv = t >> 6, lane = t & 63;
        int sg = lane >> 4, sl = lane & 15;
        for (int s = wv * 4 + sg; s < BIN_BLOCKS; s += 32) {
            int len = seglen[s], beg = segbeg[s];
            for (int j = sl; j < len; j += 16)
                atomicAdd(&hist[ebuf[beg + j] & 255], 1);
        }
        __syncthreads();
        int partial = 0;
        for (int i = t; i < b; i += 512) partial += part[i];
        red[t] = partial;
        __syncthreads();
        for (int off = 256; off > 0; off >>= 1) {
            if (t < off) red[t] += red[t + off];
            __syncthreads();
        }
        int goff = red[0];
        if (t < 256) sc[t] = hist[t];
        __syncthreads();
        for (int off = 1; off < 256; off <<= 1) {
            int a = (t < 256 && t >= off) ? sc[t - off] : 0;
            __syncthreads();
            if (t < 256) sc[t] += a;
            __syncthreads();
        }
        if (t < 256) {
            int deg = hist[t];
            int n = b * 256 + t;
            int rp = goff + sc[t] - deg;
            if (n < N_NODES) {
                rowptr[n] = rp;
                dis[n] = rsqrtf(1.0f + (float)deg);
            }
            cur[t] = rp;
        }
        if (b == 0 && t == 0) rowptr[N_NODES] = E_EDGES;
        __syncthreads();
        for (int s = wv * 4 + sg; s < BIN_BLOCKS; s += 32) {
            int len = seglen[s], beg = segbeg[s];
            for (int j = sl; j < len; j += 16) {
                uint_t v = ebuf[beg + j];
                int pos = atomicAdd(&cur[v & 255], 1);
                csr_src[pos] = (int)(v >> 8);
            }
        }
        return;
    }
    // ---- GEMM1 role: 128 rows/block, W1p staged in 2x 32KB halves ----
    int bid = blockIdx.x - NBUCK;
    int wave = threadIdx.x >> 6;
    int l = threadIdx.x & 63;
    int kg = l >> 4;
    int row = bid * 128 + wave * 16 + (l & 15);
    int rl = min(row, N_NODES - 1);
    const float* xr = x + (size_t)rl * IN_C + kg * 4;

    v4f acc[8];
    #pragma unroll
    for (int i = 0; i < 8; ++i)
        for (int r = 0; r < 4; ++r) acc[i][r] = 0.f;

    #pragma unroll
    for (int half = 0; half < 2; ++half) {
        __syncthreads();
        for (int i = threadIdx.x; i < 2048; i += 512)
            smemB[i] = ((const uint4*)W1p)[half * 2048 + i];
        float4 pa[4][2];
        #pragma unroll
        for (int i = 0; i < 4; ++i) {
            pa[i][0] = *(const float4*)(xr + (half * 4 + i) * 32);
            pa[i][1] = *(const float4*)(xr + (half * 4 + i) * 32 + 16);
        }
        __syncthreads();
        #pragma unroll
        for (int k4 = 0; k4 < 4; ++k4) {
            float4 u = pa[k4][0], v = pa[k4][1];
            v8s a;
            a[0] = f2bf(u.x); a[1] = f2bf(u.y); a[2] = f2bf(u.z); a[3] = f2bf(u.w);
            a[4] = f2bf(v.x); a[5] = f2bf(v.y); a[6] = f2bf(v.z); a[7] = f2bf(v.w);
            #pragma unroll
            for (int ct = 0; ct < 8; ++ct) {
                v8s b = ((const v8s*)smemB)[(k4 * 8 + ct) * 64 + l];
                acc[ct] = __builtin_amdgcn_mfma_f32_16x16x32_bf16(a, b, acc[ct], 0, 0, 0);
            }
        }
    }
    int orow0 = bid * 128 + wave * 16 + kg * 4;
    #pragma unroll
    for (int ct = 0; ct < 8; ++ct) {
        #pragma unroll
        for (int r = 0; r < 4; ++r) {
            int orow = orow0 + r;
            if (orow < N_NODES)
                hbf[(size_t)ct * SL + (size_t)orow * 16 + (l & 15)] = f2bf(acc[ct][r]);
        }
    }
}

// ---------- XCD-sliced aggregation, 8-lane group per node, lane = channel pair ----------
// slice = blockIdx&7 (XCD-affine). Table slice-major: tbl[s*SL + node*16 + c].
// Lane gl owns channels (2gl, 2gl+1): per edge, 8 lanes read one 32B row coalesced;
// NO cross-lane reduce per node. Unroll-4 named gathers for MLP.
template <int SPLIT>
__global__ __launch_bounds__(256) void aggregate_g(const unsigned short* __restrict__ tbl,
                                                   const int* __restrict__ csr_src,
                                                   const int* __restrict__ rowptr,
                                                   const float* __restrict__ dis,
                                                   const float* __restrict__ bias,
                                                   void* __restrict__ outp,
                                                   float* __restrict__ partials) {
    const int s = blockIdx.x & 7;
    const int chunk = blockIdx.x >> 3;             // 0..255
    const int g = threadIdx.x >> 3;                // group 0..31
    const int gl = threadIdx.x & 7;                // lane in group = channel pair
    const unsigned short* slice = tbl + (size_t)s * SL;
    const float b0 = bias[s * 16 + 2 * gl];
    const float b1 = bias[s * 16 + 2 * gl + 1];
    float sums0 = 0.f, sums1 = 0.f, sq0 = 0.f, sq1 = 0.f;

    for (int wid = chunk * 32 + g; wid < N_NODES; wid += 8192) {
        int beg = rowptr[wid], end = rowptr[wid + 1];
        float dn = dis[wid];
        uint_t su = *(const uint_t*)(slice + (size_t)wid * 16 + 2 * gl);
        float sw = dn * dn;
        float a0 = b0 + __uint_as_float(su << 16) * sw;
        float a1 = b1 + __uint_as_float(su & 0xffff0000u) * sw;
        int c = beg;
        for (; c + 4 <= end; c += 4) {
            int e0 = csr_src[c + 0], e1 = csr_src[c + 1];
            int e2 = csr_src[c + 2], e3 = csr_src[c + 3];
            float w0 = dis[e0] * dn, w1 = dis[e1] * dn;
            float w2 = dis[e2] * dn, w3 = dis[e3] * dn;
            uint_t m0 = *(const uint_t*)(slice + (size_t)e0 * 16 + 2 * gl);
            uint_t m1 = *(const uint_t*)(slice + (size_t)e1 * 16 + 2 * gl);
            uint_t m2 = *(const uint_t*)(slice + (size_t)e2 * 16 + 2 * gl);
            uint_t m3 = *(const uint_t*)(slice + (size_t)e3 * 16 + 2 * gl);
            a0 += __uint_as_float(m0 << 16) * w0; a1 += __uint_as_float(m0 & 0xffff0000u) * w0;
            a0 += __uint_as_float(m1 << 16) * w1; a1 += __uint_as_float(m1 & 0xffff0000u) * w1;
            a0 += __uint_as_float(m2 << 16) * w2; a1 += __uint_as_float(m2 & 0xffff0000u) * w2;
            a0 += __uint_as_float(m3 << 16) * w3; a1 += __uint_as_float(m3 & 0xffff0000u) * w3;
        }
        for (; c < end; ++c) {
            int e0 = csr_src[c];
            float w0 = dis[e0] * dn;
            uint_t m0 = *(const uint_t*)(slice + (size_t)e0 * 16 + 2 * gl);
            a0 += __uint_as_float(m0 << 16) * w0;
            a1 += __uint_as_float(m0 & 0xffff0000u) * w0;
        }
        if (SPLIT == 0) {
            uint_t o = ((uint_t)f2bf(a1) << 16) | f2bf(a0);
            *(uint_t*)((unsigned short*)outp + (size_t)s * SL + (size_t)wid * 16 + 2 * gl) = o;
            sums0 += a0; sq0 += a0 * a0;
            sums1 += a1; sq1 += a1 * a1;
        } else {
            float* out = (float*)outp;
            size_t base = (s < 4) ? ((size_t)wid * 64 + s * 16 + 2 * gl)
                                  : ((size_t)(N_NODES + wid) * 64 + (s - 4) * 16 + 2 * gl);
            float2 o = {a0, a1};
            *(float2*)(out + base) = o;
        }
    }
    if (SPLIT == 0) {
        __shared__ float reds[32][16], redq[32][16];
        reds[g][2 * gl] = sums0; reds[g][2 * gl + 1] = sums1;
        redq[g][2 * gl] = sq0;   redq[g][2 * gl + 1] = sq1;
        __syncthreads();
        if (threadIdx.x < 16) {
            float a = 0.f, b = 0.f;
            #pragma unroll
            for (int gg = 0; gg < 32; ++gg) { a += reds[gg][threadIdx.x]; b += redq[gg][threadIdx.x]; }
            partials[blockIdx.x * 32 + threadIdx.x] = a;
            partials[blockIdx.x * 32 + 16 + threadIdx.x] = b;
        }
    }
}

// ---------- BN reduce: one block per channel; blocks of slice s are b = chunk*8+s ----------
__global__ __launch_bounds__(256) void bn_reduce(const float* __restrict__ partials,
                                                 const float* __restrict__ gamma,
                                                 const float* __restrict__ beta,
                                                 float* __restrict__ bnab) {
    __shared__ float rs[256], rq[256];
    int c = blockIdx.x, t = threadIdx.x;
    int s = c >> 4, off = c & 15;
    rs[t] = partials[(size_t)(t * 8 + s) * 32 + off];
    rq[t] = partials[(size_t)(t * 8 + s) * 32 + 16 + off];
    __syncthreads();
    for (int o = 128; o > 0; o >>= 1) {
        if (t < o) { rs[t] += rs[t + o]; rq[t] += rq[t + o]; }
        __syncthreads();
    }
    if (t == 0) {
        float mean = rs[0] * (1.0f / N_NODES);
        float var = rq[0] * (1.0f / N_NODES) - mean * mean;
        float scale = rsqrtf(var + BN_EPS) * gamma[c];
        bnab[c] = scale;
        bnab[128 + c] = beta[c] - mean * scale;
    }
}

// ---------- GEMM2 (512 threads): slice-major bf16 in/out, BN+ReLU fused on A ----------
__global__ __launch_bounds__(512) void gemm2_bn_mfma(const unsigned short* __restrict__ h2,
                                                     const float* __restrict__ bnab,
                                                     const unsigned short* __restrict__ Wp,
                                                     unsigned short* __restrict__ Cb) {
    __shared__ uint4 wlds[2048];           // 32KB: full Wcp
    __shared__ float ss[256];
    for (int i = threadIdx.x; i < 2048; i += 512) wlds[i] = ((const uint4*)Wp)[i];
    if (threadIdx.x < 256) ss[threadIdx.x] = bnab[threadIdx.x];
    __syncthreads();

    int wave = threadIdx.x >> 6;
    int l = threadIdx.x & 63;
    int kg = l >> 4;
    int row = blockIdx.x * 128 + wave * 16 + (l & 15);
    int rl = min(row, N_NODES - 1);

    v4f acc[8];
    #pragma unroll
    for (int i = 0; i < 8; ++i)
        for (int r = 0; r < 4; ++r) acc[i][r] = 0.f;

    uint2 pa[4][2];
    #pragma unroll
    for (int i = 0; i < 4; ++i) {
        pa[i][0] = *(const uint2*)(h2 + (size_t)(2 * i) * SL + (size_t)rl * 16 + kg * 4);
        pa[i][1] = *(const uint2*)(h2 + (size_t)(2 * i + 1) * SL + (size_t)rl * 16 + kg * 4);
    }
    #pragma unroll
    for (int kt = 0; kt < HID_C / 32; ++kt) {
        int k0 = kt * 32 + kg * 4;
        float4 sc0 = *(const float4*)&ss[k0];
        float4 sh0 = *(const float4*)&ss[128 + k0];
        float4 sc1 = *(const float4*)&ss[k0 + 16];
        float4 sh1 = *(const float4*)&ss[128 + k0 + 16];
        uint2 p0 = pa[kt][0], p1 = pa[kt][1];
        float v0 = __uint_as_float(p0.x << 16), v1 = __uint_as_float(p0.x & 0xffff0000u);
        float v2 = __uint_as_float(p0.y << 16), v3 = __uint_as_float(p0.y & 0xffff0000u);
        float v4 = __uint_as_float(p1.x << 16), v5 = __uint_as_float(p1.x & 0xffff0000u);
        float v6 = __uint_as_float(p1.y << 16), v7 = __uint_as_float(p1.y & 0xffff0000u);
        v8s a;
        a[0] = f2bf(fmaxf(v0 * sc0.x + sh0.x, 0.f));
        a[1] = f2bf(fmaxf(v1 * sc0.y + sh0.y, 0.f));
        a[2] = f2bf(fmaxf(v2 * sc0.z + sh0.z, 0.f));
        a[3] = f2bf(fmaxf(v3 * sc0.w + sh0.w, 0.f));
        a[4] = f2bf(fmaxf(v4 * sc1.x + sh1.x, 0.f));
        a[5] = f2bf(fmaxf(v5 * sc1.y + sh1.y, 0.f));
        a[6] = f2bf(fmaxf(v6 * sc1.z + sh1.z, 0.f));
        a[7] = f2bf(fmaxf(v7 * sc1.w + sh1.w, 0.f));
        #pragma unroll
        for (int ct = 0; ct < 8; ++ct) {
            v8s b = ((const v8s*)wlds)[(kt * 8 + ct) * 64 + l];
            acc[ct] = __builtin_amdgcn_mfma_f32_16x16x32_bf16(a, b, acc[ct], 0, 0, 0);
        }
    }
    int orow0 = blockIdx.x * 128 + wave * 16 + kg * 4;
    #pragma unroll
    for (int ct = 0; ct < 8; ++ct) {
        #pragma unroll
        for (int r = 0; r < 4; ++r) {
            int orow = orow0 + r;
            if (orow < N_NODES)
                Cb[(size_t)ct * SL + (size_t)orow * 16 + (l & 15)] = f2bf(acc[ct][r]);
        }
    }
}

extern "C" void kernel_launch(void* const* d_in, const int* in_sizes, int n_in,
                              void* d_out, int out_size, void* d_ws, size_t ws_size,
                              hipStream_t stream) {
    const float* x    = (const float*)d_in[0];
    const int* ei     = (const int*)d_in[1];
    const float* W1   = (const float*)d_in[2];
    const float* b1   = (const float*)d_in[3];
    const float* gamma= (const float*)d_in[4];
    const float* beta = (const float*)d_in[5];
    const float* W2   = (const float*)d_in[6];
    const float* b2   = (const float*)d_in[7];
    const float* W3   = (const float*)d_in[8];
    const float* b3   = (const float*)d_in[9];
    float* out = (float*)d_out;

    char* p = (char*)d_ws;
    auto alloc = [&](size_t bytes) {
        void* r = (void*)p;
        p += (bytes + 511) & ~(size_t)511;
        return r;
    };
    float* dis    = (float*)alloc(N_NODES * 4);
    int*   rowptr = (int*)  alloc((N_NODES + 1) * 4);
    int*   part   = (int*)  alloc(2048);
    float* bnab   = (float*)alloc(1024);
    float* bcat   = (float*)alloc(512);
    unsigned short* W1p = (unsigned short*)alloc(256 * 128 * 2);
    unsigned short* Wcp = (unsigned short*)alloc(128 * 128 * 2);
    int*   H      = (int*)  alloc((size_t)BIN_BLOCKS * HW * 4);
    uint_t* ebuf  = (uint_t*)alloc((size_t)E_EDGES * 4);
    int*   csrs   = (int*)  alloc((size_t)E_EDGES * 4);
    unsigned short* hbf  = (unsigned short*)alloc((size_t)N_NODES * 128 * 2);  // gemm1/gemm2 out (slice-major)
    unsigned short* h2bf = (unsigned short*)alloc((size_t)N_NODES * 128 * 2);  // agg1 out (slice-major)
    float* partials = (float*)alloc((size_t)AGG_BLOCKS * 32 * 4);

    hipMemsetAsync(part, 0, 2048, stream);

    // edge binning (+inline dtype detect, +global bucket counts) || weight permutes
    bin_kernel<<<BIN_BLOCKS + WPERM_BLOCKS, 512, 0, stream>>>(
        ei, ebuf, H, part, W1, W2, W3, b2, b3, W1p, Wcp, bcat);

    // {bucket hist + scan + csr fill} || GEMM1 (slice-major out)
    scanfill_and_gemm1<<<NBUCK + GB1, 512, 0, stream>>>(ebuf, H, part, rowptr, dis, csrs,
                                                        x, W1p, hbf);

    // layer 1 aggregate (XCD-sliced, group-per-node) + BN partials
    aggregate_g<0><<<AGG_BLOCKS, 256, 0, stream>>>(hbf, csrs, rowptr, dis, b1,
                                                   (void*)h2bf, partials);
    bn_reduce<<<128, 256, 0, stream>>>(partials, gamma, beta, bnab);

    // layer 2: BN+ReLU fused into GEMM2 (slice-major in/out)
    gemm2_bn_mfma<<<GB2, 512, 0, stream>>>(h2bf, bnab, Wcp, hbf);
    aggregate_g<1><<<AGG_BLOCKS, 256, 0, stream>>>(hbf, csrs, rowptr, dis, bcat,
                                                   (void*)out, partials);
}

// Round 17
// 220.045 us; speedup vs baseline: 1.9196x; 1.6752x over previous
//
#include <hip/hip_runtime.h>

#define N_NODES 100000
#define E_EDGES 1600000
#define IN_C 256
#define HID_C 128
#define BN_EPS 1e-5f

#define NBUCK 391                      // buckets of 256 nodes: dst >> 8
#define BIN_BLOCKS 256
#define CHUNK (E_EDGES / BIN_BLOCKS)   // 6250
#define HW 392                         // segment-table row width (incl. sentinel)
#define AGG_BLOCKS 2048                // aggregate grid
#define GB1 782                        // gemm1 blocks: 128 rows each
#define GB2 782                        // gemm2 blocks: 128 rows each
#define WPERM_BLOCKS 97                // 49280 permute elems / 512

typedef unsigned int uint_t;
using v8s = __attribute__((ext_vector_type(8))) short;
using v4f = __attribute__((ext_vector_type(4))) float;

__device__ __forceinline__ unsigned short f2bf(float f) {
    unsigned int u = __float_as_uint(f);
    u += 0x7fffu + ((u >> 16) & 1u);
    return (unsigned short)(u >> 16);
}

__device__ __forceinline__ void fma8(uint4 u, float w, float* a) {
    a[0] += __uint_as_float(u.x << 16) * w;
    a[1] += __uint_as_float(u.x & 0xffff0000u) * w;
    a[2] += __uint_as_float(u.y << 16) * w;
    a[3] += __uint_as_float(u.y & 0xffff0000u) * w;
    a[4] += __uint_as_float(u.z << 16) * w;
    a[5] += __uint_as_float(u.z & 0xffff0000u) * w;
    a[6] += __uint_as_float(u.w << 16) * w;
    a[7] += __uint_as_float(u.w & 0xffff0000u) * w;
}

// ---------- edge index accessors ----------
__device__ __forceinline__ int edge_src(const int* ei, int e, int is64) {
    return is64 ? ei[2 * e] : ei[e];
}
__device__ __forceinline__ int edge_dst(const int* ei, int e, int is64) {
    return is64 ? ei[2 * E_EDGES + 2 * e] : ei[E_EDGES + e];
}

// ---------- bin (blocks<256: counting sort by dst>>8, inline dtype detect)
//            + wperm role (blocks >= 256) ----------
__global__ __launch_bounds__(512) void bin_kernel(
    const int* __restrict__ ei, uint_t* __restrict__ ebuf, int* __restrict__ H,
    int* __restrict__ part,
    const float* __restrict__ W1, const float* __restrict__ W2,
    const float* __restrict__ W3, const float* __restrict__ b2,
    const float* __restrict__ b3,
    unsigned short* __restrict__ W1p, unsigned short* __restrict__ Wcp,
    float* __restrict__ bcat) {
    if (blockIdx.x >= BIN_BLOCKS) {
        int t = (blockIdx.x - BIN_BLOCKS) * 512 + threadIdx.x;
        if (t < 32768) {                       // W1p: K=256
            int j = t & 7, l = (t >> 3) & 63, ct = (t >> 9) & 7, kt = t >> 12;
            int k = kt * 32 + ((l >> 4) << 2) + (j & 3) + ((j >> 2) << 4);
            int n = ct * 16 + (l & 15);
            W1p[t] = f2bf(W1[k * 128 + n]);
        } else if (t < 49152) {                // Wcp: K=128, cols = [W2|W3]
            int u = t - 32768;
            int j = u & 7, l = (u >> 3) & 63, ct = (u >> 9) & 7, kt = u >> 12;
            int k = kt * 32 + ((l >> 4) << 2) + (j & 3) + ((j >> 2) << 4);
            int n = ct * 16 + (l & 15);
            float v = (n < 64) ? W2[k * 64 + n] : W3[k * 64 + (n - 64)];
            Wcp[u] = f2bf(v);
        } else if (t < 49280) {
            int c = t - 49152;
            bcat[c] = (c < 64) ? b2[c] : b3[c - 64];
        }
        return;
    }
    __shared__ int sh[512];
    __shared__ int cur[512];
    __shared__ int anyw;
    int tid = threadIdx.x;
    int base = blockIdx.x * CHUNK;
    if (tid == 0) anyw = 0;
    sh[tid] = 0;
    __syncthreads();
    if (ei[2 * (base + tid) + 1] != 0) atomicOr(&anyw, 1);
    __syncthreads();
    int is64 = anyw ? 0 : 1;
    for (int i = tid; i < CHUNK; i += 512)
        atomicAdd(&sh[edge_dst(ei, base + i, is64) >> 8], 1);
    __syncthreads();
    int c0 = sh[tid];
    if (tid < NBUCK && c0 > 0) atomicAdd(&part[tid], c0);
    for (int off = 1; off < 512; off <<= 1) {
        int a0 = (tid >= off) ? sh[tid - off] : 0;
        __syncthreads();
        sh[tid] += a0;
        __syncthreads();
    }
    int ex = sh[tid] - c0;
    cur[tid] = ex;
    if (tid < HW) H[blockIdx.x * HW + tid] = ex;
    __syncthreads();
    for (int i = tid; i < CHUNK; i += 512) {
        int e = base + i;
        int s = edge_src(ei, e, is64);
        int d = edge_dst(ei, e, is64);
        int pos = base + atomicAdd(&cur[d >> 8], 1);
        ebuf[pos] = ((uint_t)s << 8) | (uint_t)(d & 255);
    }
}

// ---------- fused (512 thr): {bucket hist + scan + csr fill} || GEMM1 ----------
__global__ __launch_bounds__(512) void scanfill_and_gemm1(
    const uint_t* __restrict__ ebuf, const int* __restrict__ H,
    const int* __restrict__ part, int* __restrict__ rowptr,
    float* __restrict__ dis, int* __restrict__ csr_src,
    const float* __restrict__ x, const unsigned short* __restrict__ W1p,
    unsigned short* __restrict__ hbf) {
    __shared__ uint4 smemB[2048];          // 32KB (gemm role); aliased by scan role
    if (blockIdx.x < NBUCK) {
        int* segbeg = (int*)smemB;
        int* seglen = segbeg + 256;
        int* hist   = seglen + 256;
        int* sc     = hist + 256;
        int* cur    = sc + 256;
        int* red    = cur + 256;
        int t = threadIdx.x, b = blockIdx.x;
        if (t < 256) {
            int h0 = H[t * HW + b], h1 = H[t * HW + b + 1];
            segbeg[t] = t * CHUNK + h0;
            seglen[t] = h1 - h0;
            hist[t] = 0;
        }
        __syncthreads();
        int wv = t >> 6, lane = t & 63;
        int sg = lane >> 4, sl = lane & 15;
        for (int s = wv * 4 + sg; s < BIN_BLOCKS; s += 32) {
            int len = seglen[s], beg = segbeg[s];
            for (int j = sl; j < len; j += 16)
                atomicAdd(&hist[ebuf[beg + j] & 255], 1);
        }
        __syncthreads();
        int partial = 0;
        for (int i = t; i < b; i += 512) partial += part[i];
        red[t] = partial;
        __syncthreads();
        for (int off = 256; off > 0; off >>= 1) {
            if (t < off) red[t] += red[t + off];
            __syncthreads();
        }
        int goff = red[0];
        if (t < 256) sc[t] = hist[t];
        __syncthreads();
        for (int off = 1; off < 256; off <<= 1) {
            int a = (t < 256 && t >= off) ? sc[t - off] : 0;
            __syncthreads();
            if (t < 256) sc[t] += a;
            __syncthreads();
        }
        if (t < 256) {
            int deg = hist[t];
            int n = b * 256 + t;
            int rp = goff + sc[t] - deg;
            if (n < N_NODES) {
                rowptr[n] = rp;
                dis[n] = rsqrtf(1.0f + (float)deg);
            }
            cur[t] = rp;
        }
        if (b == 0 && t == 0) rowptr[N_NODES] = E_EDGES;
        __syncthreads();
        for (int s = wv * 4 + sg; s < BIN_BLOCKS; s += 32) {
            int len = seglen[s], beg = segbeg[s];
            for (int j = sl; j < len; j += 16) {
                uint_t v = ebuf[beg + j];
                int pos = atomicAdd(&cur[v & 255], 1);
                csr_src[pos] = (int)(v >> 8);
            }
        }
        return;
    }
    // ---- GEMM1 role: 128 rows/block, W1p staged in 2x 32KB halves ----
    int bid = blockIdx.x - NBUCK;
    int wave = threadIdx.x >> 6;
    int l = threadIdx.x & 63;
    int kg = l >> 4;
    int row = bid * 128 + wave * 16 + (l & 15);
    int rl = min(row, N_NODES - 1);
    const float* xr = x + (size_t)rl * IN_C + kg * 4;

    v4f acc[8];
    #pragma unroll
    for (int i = 0; i < 8; ++i)
        for (int r = 0; r < 4; ++r) acc[i][r] = 0.f;

    #pragma unroll
    for (int half = 0; half < 2; ++half) {
        __syncthreads();
        for (int i = threadIdx.x; i < 2048; i += 512)
            smemB[i] = ((const uint4*)W1p)[half * 2048 + i];
        float4 pa[4][2];
        #pragma unroll
        for (int i = 0; i < 4; ++i) {
            pa[i][0] = *(const float4*)(xr + (half * 4 + i) * 32);
            pa[i][1] = *(const float4*)(xr + (half * 4 + i) * 32 + 16);
        }
        __syncthreads();
        #pragma unroll
        for (int k4 = 0; k4 < 4; ++k4) {
            float4 u = pa[k4][0], v = pa[k4][1];
            v8s a;
            a[0] = f2bf(u.x); a[1] = f2bf(u.y); a[2] = f2bf(u.z); a[3] = f2bf(u.w);
            a[4] = f2bf(v.x); a[5] = f2bf(v.y); a[6] = f2bf(v.z); a[7] = f2bf(v.w);
            #pragma unroll
            for (int ct = 0; ct < 8; ++ct) {
                v8s b = ((const v8s*)smemB)[(k4 * 8 + ct) * 64 + l];
                acc[ct] = __builtin_amdgcn_mfma_f32_16x16x32_bf16(a, b, acc[ct], 0, 0, 0);
            }
        }
    }
    int orow0 = bid * 128 + wave * 16 + kg * 4;
    #pragma unroll
    for (int ct = 0; ct < 8; ++ct) {
        #pragma unroll
        for (int r = 0; r < 4; ++r) {
            int orow = orow0 + r;
            if (orow < N_NODES)
                hbf[(size_t)orow * 128 + ct * 16 + (l & 15)] = f2bf(acc[ct][r]);
        }
    }
}

// ---------- independent-quarter CSR aggregation, 8 named gathers in flight ----------
template <int SPLIT>
__global__ __launch_bounds__(256) void aggregate_q(const uint4* __restrict__ hb4,
                                                   const int* __restrict__ csr_src,
                                                   const int* __restrict__ rowptr,
                                                   const float* __restrict__ dis,
                                                   const float* __restrict__ bias,
                                                   void* __restrict__ outp,
                                                   float* __restrict__ partials) {
    int lane = threadIdx.x & 63;
    int wv = threadIdx.x >> 6;
    int qg = lane >> 4, ql = lane & 15;            // quarter group / quarter lane
    float4 bv0 = ((const float4*)bias)[ql * 2];
    float4 bv1 = ((const float4*)bias)[ql * 2 + 1];
    float bs[8] = {bv0.x, bv0.y, bv0.z, bv0.w, bv1.x, bv1.y, bv1.z, bv1.w};
    float sums[8] = {}, sumsq[8] = {};
    const char* hbp = (const char*)hb4;
    const uint_t qoff = (uint_t)ql << 4;
    const int Q = blockIdx.x * 16 + wv * 4 + qg;   // global quarter id

    for (int wid = Q; wid < N_NODES; wid += AGG_BLOCKS * 16) {
        int beg = rowptr[wid], end = rowptr[wid + 1];
        float dn = dis[wid];
        float sw = dn * dn;
        uint4 su = *(const uint4*)(hbp + (((uint_t)wid << 8) | qoff));
        float a[8];
        #pragma unroll
        for (int k = 0; k < 8; ++k) a[k] = bs[k];
        fma8(su, sw, a);
        for (int c = beg; c < end; c += 16) {
            int idx = c + ql;
            int slv = (idx < end) ? csr_src[idx] : 0;
            float wlv = (idx < end) ? dis[slv] * dn : 0.0f;
            int cnt = min(16, end - c);
            for (int j = 0; j < cnt; j += 8) {     // 8 named gathers in flight
                int l0 = (qg << 4) + j;
                int e0 = __shfl(slv, l0 + 0), e1 = __shfl(slv, l0 + 1);
                int e2 = __shfl(slv, l0 + 2), e3 = __shfl(slv, l0 + 3);
                int e4 = __shfl(slv, l0 + 4), e5 = __shfl(slv, l0 + 5);
                int e6 = __shfl(slv, l0 + 6), e7 = __shfl(slv, l0 + 7);
                float w0 = __shfl(wlv, l0 + 0), w1 = __shfl(wlv, l0 + 1);
                float w2 = __shfl(wlv, l0 + 2), w3 = __shfl(wlv, l0 + 3);
                float w4 = __shfl(wlv, l0 + 4), w5 = __shfl(wlv, l0 + 5);
                float w6 = __shfl(wlv, l0 + 6), w7 = __shfl(wlv, l0 + 7);
                uint4 u0 = *(const uint4*)(hbp + (((uint_t)e0 << 8) | qoff));
                uint4 u1 = *(const uint4*)(hbp + (((uint_t)e1 << 8) | qoff));
                uint4 u2 = *(const uint4*)(hbp + (((uint_t)e2 << 8) | qoff));
                uint4 u3 = *(const uint4*)(hbp + (((uint_t)e3 << 8) | qoff));
                uint4 u4 = *(const uint4*)(hbp + (((uint_t)e4 << 8) | qoff));
                uint4 u5 = *(const uint4*)(hbp + (((uint_t)e5 << 8) | qoff));
                uint4 u6 = *(const uint4*)(hbp + (((uint_t)e6 << 8) | qoff));
                uint4 u7 = *(const uint4*)(hbp + (((uint_t)e7 << 8) | qoff));
                fma8(u0, w0, a); fma8(u1, w1, a);
                fma8(u2, w2, a); fma8(u3, w3, a);
                fma8(u4, w4, a); fma8(u5, w5, a);
                fma8(u6, w6, a); fma8(u7, w7, a);
            }
        }
        if (SPLIT == 0) {
            uint4 o;
            o.x = ((uint_t)f2bf(a[1]) << 16) | f2bf(a[0]);
            o.y = ((uint_t)f2bf(a[3]) << 16) | f2bf(a[2]);
            o.z = ((uint_t)f2bf(a[5]) << 16) | f2bf(a[4]);
            o.w = ((uint_t)f2bf(a[7]) << 16) | f2bf(a[6]);
            *(uint4*)((char*)outp + (((uint_t)wid << 8) | qoff)) = o;
            #pragma unroll
            for (int k = 0; k < 8; ++k) { sums[k] += a[k]; sumsq[k] += a[k] * a[k]; }
        } else {
            float* out = (float*)outp;
            size_t base = (ql < 8) ? ((size_t)wid * 64 + ql * 8)
                                   : ((size_t)(N_NODES + wid) * 64 + (ql - 8) * 8);
            float4 o0 = {a[0], a[1], a[2], a[3]};
            float4 o1 = {a[4], a[5], a[6], a[7]};
            *(float4*)(out + base) = o0;
            *(float4*)(out + base + 4) = o1;
        }
    }
    if (SPLIT == 0) {
        #pragma unroll
        for (int k = 0; k < 8; ++k) {
            sums[k] += __shfl_xor(sums[k], 16);
            sums[k] += __shfl_xor(sums[k], 32);
            sumsq[k] += __shfl_xor(sumsq[k], 16);
            sumsq[k] += __shfl_xor(sumsq[k], 32);
        }
        __shared__ float red[4][256];
        if (qg == 0) {
            int c = ql * 8;
            #pragma unroll
            for (int k = 0; k < 8; ++k) {
                red[wv][c + k] = sums[k];
                red[wv][128 + c + k] = sumsq[k];
            }
        }
        __syncthreads();
        int t = threadIdx.x;
        partials[blockIdx.x * 256 + t] =
            red[0][t] + red[1][t] + red[2][t] + red[3][t];
    }
}

// ---------- parallel BN reduce: one block per channel ----------
__global__ __launch_bounds__(256) void bn_reduce(const float* __restrict__ partials,
                                                 const float* __restrict__ gamma,
                                                 const float* __restrict__ beta,
                                                 float* __restrict__ bnab) {
    __shared__ float rs[256], rq[256];
    int c = blockIdx.x, t = threadIdx.x;
    float s = 0.f, q = 0.f;
    for (int i = t; i < AGG_BLOCKS; i += 256) {
        s += partials[i * 256 + c];
        q += partials[i * 256 + 128 + c];
    }
    rs[t] = s; rq[t] = q;
    __syncthreads();
    for (int off = 128; off > 0; off >>= 1) {
        if (t < off) { rs[t] += rs[t + off]; rq[t] += rq[t + off]; }
        __syncthreads();
    }
    if (t == 0) {
        float mean = rs[0] * (1.0f / N_NODES);
        float var = rq[0] * (1.0f / N_NODES) - mean * mean;
        float scale = rsqrtf(var + BN_EPS) * gamma[c];
        bnab[c] = scale;
        bnab[128 + c] = beta[c] - mean * scale;
    }
}

// ---------- GEMM2 (512 threads): bf16 in, BN+ReLU fused on A, B staged in LDS ----------
__global__ __launch_bounds__(512) void gemm2_bn_mfma(const unsigned short* __restrict__ h2,
                                                     const float* __restrict__ bnab,
                                                     const unsigned short* __restrict__ Wp,
                                                     unsigned short* __restrict__ Cb) {
    __shared__ uint4 wlds[2048];           // 32KB: full Wcp
    __shared__ float ss[256];
    for (int i = threadIdx.x; i < 2048; i += 512) wlds[i] = ((const uint4*)Wp)[i];
    if (threadIdx.x < 256) ss[threadIdx.x] = bnab[threadIdx.x];
    __syncthreads();

    int wave = threadIdx.x >> 6;
    int l = threadIdx.x & 63;
    int kg = l >> 4;
    int row = blockIdx.x * 128 + wave * 16 + (l & 15);
    int rl = min(row, N_NODES - 1);
    const unsigned short* ar = h2 + (size_t)rl * HID_C + kg * 4;

    v4f acc[8];
    #pragma unroll
    for (int i = 0; i < 8; ++i)
        for (int r = 0; r < 4; ++r) acc[i][r] = 0.f;

    uint2 pa[4][2];
    #pragma unroll
    for (int i = 0; i < 4; ++i) {
        pa[i][0] = *(const uint2*)(ar + i * 32);
        pa[i][1] = *(const uint2*)(ar + i * 32 + 16);
    }
    #pragma unroll
    for (int kt = 0; kt < HID_C / 32; ++kt) {
        int k0 = kt * 32 + kg * 4;
        float4 sc0 = *(const float4*)&ss[k0];
        float4 sh0 = *(const float4*)&ss[128 + k0];
        float4 sc1 = *(const float4*)&ss[k0 + 16];
        float4 sh1 = *(const float4*)&ss[128 + k0 + 16];
        uint2 p0 = pa[kt][0], p1 = pa[kt][1];
        float v0 = __uint_as_float(p0.x << 16), v1 = __uint_as_float(p0.x & 0xffff0000u);
        float v2 = __uint_as_float(p0.y << 16), v3 = __uint_as_float(p0.y & 0xffff0000u);
        float v4 = __uint_as_float(p1.x << 16), v5 = __uint_as_float(p1.x & 0xffff0000u);
        float v6 = __uint_as_float(p1.y << 16), v7 = __uint_as_float(p1.y & 0xffff0000u);
        v8s a;
        a[0] = f2bf(fmaxf(v0 * sc0.x + sh0.x, 0.f));
        a[1] = f2bf(fmaxf(v1 * sc0.y + sh0.y, 0.f));
        a[2] = f2bf(fmaxf(v2 * sc0.z + sh0.z, 0.f));
        a[3] = f2bf(fmaxf(v3 * sc0.w + sh0.w, 0.f));
        a[4] = f2bf(fmaxf(v4 * sc1.x + sh1.x, 0.f));
        a[5] = f2bf(fmaxf(v5 * sc1.y + sh1.y, 0.f));
        a[6] = f2bf(fmaxf(v6 * sc1.z + sh1.z, 0.f));
        a[7] = f2bf(fmaxf(v7 * sc1.w + sh1.w, 0.f));
        #pragma unroll
        for (int ct = 0; ct < 8; ++ct) {
            v8s b = ((const v8s*)wlds)[(kt * 8 + ct) * 64 + l];
            acc[ct] = __builtin_amdgcn_mfma_f32_16x16x32_bf16(a, b, acc[ct], 0, 0, 0);
        }
    }
    int orow0 = blockIdx.x * 128 + wave * 16 + kg * 4;
    #pragma unroll
    for (int ct = 0; ct < 8; ++ct) {
        #pragma unroll
        for (int r = 0; r < 4; ++r) {
            int orow = orow0 + r;
            if (orow < N_NODES)
                Cb[(size_t)orow * 128 + ct * 16 + (l & 15)] = f2bf(acc[ct][r]);
        }
    }
}

extern "C" void kernel_launch(void* const* d_in, const int* in_sizes, int n_in,
                              void* d_out, int out_size, void* d_ws, size_t ws_size,
                              hipStream_t stream) {
    const float* x    = (const float*)d_in[0];
    const int* ei     = (const int*)d_in[1];
    const float* W1   = (const float*)d_in[2];
    const float* b1   = (const float*)d_in[3];
    const float* gamma= (const float*)d_in[4];
    const float* beta = (const float*)d_in[5];
    const float* W2   = (const float*)d_in[6];
    const float* b2   = (const float*)d_in[7];
    const float* W3   = (const float*)d_in[8];
    const float* b3   = (const float*)d_in[9];
    float* out = (float*)d_out;

    char* p = (char*)d_ws;
    auto alloc = [&](size_t bytes) {
        void* r = (void*)p;
        p += (bytes + 511) & ~(size_t)511;
        return r;
    };
    float* dis    = (float*)alloc(N_NODES * 4);
    int*   rowptr = (int*)  alloc((N_NODES + 1) * 4);
    int*   part   = (int*)  alloc(2048);
    float* bnab   = (float*)alloc(1024);
    float* bcat   = (float*)alloc(512);
    unsigned short* W1p = (unsigned short*)alloc(256 * 128 * 2);
    unsigned short* Wcp = (unsigned short*)alloc(128 * 128 * 2);
    int*   H      = (int*)  alloc((size_t)BIN_BLOCKS * HW * 4);
    uint_t* ebuf  = (uint_t*)alloc((size_t)E_EDGES * 4);
    int*   csrs   = (int*)  alloc((size_t)E_EDGES * 4);
    uint_t* hbf   = (uint_t*)alloc((size_t)N_NODES * 64 * 4);   // gemm1 out / gemm2 out
    uint_t* h2bf  = (uint_t*)alloc((size_t)N_NODES * 64 * 4);   // agg1 bf16 out
    float* partials = (float*)alloc((size_t)AGG_BLOCKS * 256 * 4);

    hipMemsetAsync(part, 0, 2048, stream);

    // edge binning (+inline dtype detect, +global bucket counts) || weight permutes
    bin_kernel<<<BIN_BLOCKS + WPERM_BLOCKS, 512, 0, stream>>>(
        ei, ebuf, H, part, W1, W2, W3, b2, b3, W1p, Wcp, bcat);

    // {bucket hist + scan + csr fill} || GEMM1
    scanfill_and_gemm1<<<NBUCK + GB1, 512, 0, stream>>>(ebuf, H, part, rowptr, dis, csrs,
                                                        x, W1p, (unsigned short*)hbf);

    // layer 1 aggregate + fused BN partials; emits bf16
    aggregate_q<0><<<AGG_BLOCKS, 256, 0, stream>>>((const uint4*)hbf, csrs, rowptr, dis,
                                                   b1, (void*)h2bf, partials);
    bn_reduce<<<128, 256, 0, stream>>>(partials, gamma, beta, bnab);

    // layer 2: BN+ReLU fused into GEMM2's A-path; out bf16 into hbf (dead)
    gemm2_bn_mfma<<<GB2, 512, 0, stream>>>((const unsigned short*)h2bf, bnab, Wcp,
                                           (unsigned short*)hbf);
    aggregate_q<1><<<AGG_BLOCKS, 256, 0, stream>>>((const uint4*)hbf, csrs, rowptr, dis,
                                                   bcat, (void*)out, partials);
}